// Round 1
// baseline (418.481 us; speedup 1.0000x reference)
//
#include <hip/hip_runtime.h>

// GCN 2-layer: x[100000,64] @ W1[64,64] -> scatter-norm-agg -> +b1,relu
//              -> @ W2[64,32] -> scatter-norm-agg -> +b2 -> log_softmax
constexpr int N  = 100000;
constexpr int E  = 800000;
constexpr int C1 = 64;   // IN_CH
constexpr int C2 = 64;   // HID_CH
constexpr int C3 = 32;   // OUT_CH

// ---------------- degree ----------------
__global__ void k_degree(const int* __restrict__ dst, int* __restrict__ deg) {
    int e = blockIdx.x * blockDim.x + threadIdx.x;
    if (e < E) atomicAdd(&deg[dst[e]], 1);
}

__global__ void k_dis(const int* __restrict__ deg, float* __restrict__ dis) {
    int i = blockIdx.x * blockDim.x + threadIdx.x;
    if (i < N) dis[i] = rsqrtf((float)(deg[i] + 1));  // +1 = self-loop
}

// ---------------- dense GEMM  H[N,COUT] = X[N,CIN] @ W[CIN,COUT] ----------------
template <int CIN, int COUT>
__global__ void k_gemm(const float* __restrict__ X, const float* __restrict__ W,
                       float* __restrict__ H) {
    constexpr int ROWS = 256 / COUT;            // rows per block
    __shared__ float sW[CIN * COUT];
    __shared__ float sX[ROWS][CIN];
    for (int i = threadIdx.x; i < CIN * COUT; i += 256) sW[i] = W[i];
    int row0 = blockIdx.x * ROWS;
    for (int i = threadIdx.x; i < ROWS * CIN; i += 256) {
        int r = i / CIN, c = i % CIN;
        int gr = row0 + r;
        sX[r][c] = (gr < N) ? X[(long)gr * CIN + c] : 0.f;
    }
    __syncthreads();
    int r = threadIdx.x / COUT;
    int c = threadIdx.x % COUT;
    int gr = row0 + r;
    if (gr >= N) return;
    float acc = 0.f;
#pragma unroll
    for (int k = 0; k < CIN; ++k) acc += sX[r][k] * sW[k * COUT + c];
    H[(long)gr * COUT + c] = acc;
}

// ---------------- edge scatter: AGG[dst] += H[src] * dis[src]*dis[dst] ----------------
template <int C>
__global__ void k_scatter(const int* __restrict__ src, const int* __restrict__ dst,
                          const float* __restrict__ dis, const float* __restrict__ H,
                          float* __restrict__ AGG) {
    unsigned gid = blockIdx.x * blockDim.x + threadIdx.x;
    unsigned e = gid / C;
    unsigned c = gid % C;
    if (e >= E) return;
    int s = src[e], d = dst[e];
    float norm = dis[s] * dis[d];
    atomicAdd(&AGG[(long)d * C + c], H[(long)s * C + c] * norm);
}

// ---------------- layer-1 epilogue: self-loop + bias + relu (in place on AGG) ----------------
__global__ void k_self_bias_relu(const float* __restrict__ H, const float* __restrict__ dis,
                                 const float* __restrict__ b, float* __restrict__ AGG) {
    unsigned gid = blockIdx.x * blockDim.x + threadIdx.x;
    if (gid >= (unsigned)N * C2) return;
    unsigned i = gid / C2, c = gid % C2;
    float dd = dis[i];
    float v = AGG[gid] + H[gid] * dd * dd + b[c];
    AGG[gid] = fmaxf(v, 0.f);
}

// ---------------- layer-2 epilogue: self-loop + bias + log_softmax (in place on OUT) --------
__global__ void k_finalize(const float* __restrict__ H2, const float* __restrict__ dis,
                           const float* __restrict__ b, float* __restrict__ OUT) {
    unsigned gid = blockIdx.x * blockDim.x + threadIdx.x;
    unsigned node = gid / C3;
    unsigned c = gid % C3;
    if (node >= (unsigned)N) return;
    float dd = dis[node];
    float v = OUT[gid] + H2[gid] * dd * dd + b[c];
    // log_softmax across the 32 channels of this node (32-lane subgroup reduce)
    float m = v;
#pragma unroll
    for (int off = 16; off >= 1; off >>= 1) m = fmaxf(m, __shfl_xor(m, off, 32));
    float ex = expf(v - m);
    float s = ex;
#pragma unroll
    for (int off = 16; off >= 1; off >>= 1) s += __shfl_xor(s, off, 32);
    OUT[gid] = v - m - logf(s);
}

extern "C" void kernel_launch(void* const* d_in, const int* in_sizes, int n_in,
                              void* d_out, int out_size, void* d_ws, size_t ws_size,
                              hipStream_t stream) {
    const float* x    = (const float*)d_in[0];
    const int*   ei   = (const int*)d_in[1];
    const float* W1   = (const float*)d_in[2];
    const float* b1   = (const float*)d_in[3];
    const float* W2   = (const float*)d_in[4];
    const float* b2   = (const float*)d_in[5];
    float* out = (float*)d_out;

    const int* src = ei;        // edge_index[0]
    const int* dst = ei + E;    // edge_index[1]

    char* ws = (char*)d_ws;
    int*   deg  = (int*)(ws);                                  // N ints   (0.4 MB)
    float* dis  = (float*)(ws + (size_t)N * 4);                // N f32    (0.4 MB)
    float* h1   = (float*)(ws + (size_t)N * 8);                // N*64 f32 (25.6 MB)
    float* agg1 = (float*)(ws + (size_t)N * 8 + (size_t)N * C2 * 4);          // N*64 f32
    float* h2   = (float*)(ws + (size_t)N * 8 + (size_t)N * C2 * 8);          // N*32 f32

    // zero accumulators (capture-safe async memsets)
    hipMemsetAsync(deg,  0, (size_t)N * 4, stream);
    hipMemsetAsync(agg1, 0, (size_t)N * C2 * 4, stream);
    hipMemsetAsync(out,  0, (size_t)N * C3 * 4, stream);

    k_degree<<<(E + 255) / 256, 256, 0, stream>>>(dst, deg);
    k_dis<<<(N + 255) / 256, 256, 0, stream>>>(deg, dis);

    // layer 1
    k_gemm<C1, C2><<<(N + 3) / 4, 256, 0, stream>>>(x, W1, h1);
    k_scatter<C2><<<(unsigned)((long)E * C2 / 256), 256, 0, stream>>>(src, dst, dis, h1, agg1);
    k_self_bias_relu<<<((unsigned)N * C2 + 255) / 256, 256, 0, stream>>>(h1, dis, b1, agg1);

    // layer 2
    k_gemm<C2, C3><<<(N + 7) / 8, 256, 0, stream>>>(agg1, W2, h2);
    k_scatter<C3><<<(unsigned)((long)E * C3 / 256), 256, 0, stream>>>(src, dst, dis, h2, out);
    k_finalize<<<((unsigned)N * C3 + 255) / 256, 256, 0, stream>>>(h2, dis, b2, out);
}

// Round 2
// 311.984 us; speedup vs baseline: 1.3414x; 1.3414x over previous
//
#include <hip/hip_runtime.h>

// GCN 2-layer via CSR gather (no float atomics):
//   deg -> rsqrt norm -> CSR build (scan + place) ->
//   gemm1 -> gather1(+bias+relu) -> gemm2 -> gather2(+bias+log_softmax)
constexpr int N  = 100000;
constexpr int E  = 800000;
constexpr int C1 = 64;   // IN_CH
constexpr int C2 = 64;   // HID_CH
constexpr int C3 = 32;   // OUT_CH
constexpr int CHUNK = 1024;
constexpr int NB = (N + CHUNK - 1) / CHUNK;   // 98 scan blocks

// ---------------- degree ----------------
__global__ void k_degree(const int* __restrict__ dst, int* __restrict__ deg) {
    int e = blockIdx.x * blockDim.x + threadIdx.x;
    if (e < E) atomicAdd(&deg[dst[e]], 1);
}

__global__ void k_dis(const int* __restrict__ deg, float* __restrict__ dis) {
    int i = blockIdx.x * blockDim.x + threadIdx.x;
    if (i < N) dis[i] = rsqrtf((float)(deg[i] + 1));  // +1 = self-loop
}

// ---------------- exclusive scan of deg -> rowptr (3 kernels) ----------------
__global__ void k_scanA(const int* __restrict__ deg, int* __restrict__ rowptr,
                        int* __restrict__ bsum) {
    __shared__ int a[2][256];
    int b = blockIdx.x, t = threadIdx.x;
    int base = b * CHUNK + t * 4;
    int v[4];
#pragma unroll
    for (int k = 0; k < 4; ++k) v[k] = (base + k < N) ? deg[base + k] : 0;
    int mysum = v[0] + v[1] + v[2] + v[3];
    a[0][t] = mysum;
    __syncthreads();
    int pin = 0;
    for (int off = 1; off < 256; off <<= 1) {
        int x = a[pin][t];
        if (t >= off) x += a[pin][t - off];
        a[pin ^ 1][t] = x;
        __syncthreads();
        pin ^= 1;
    }
    int incl = a[pin][t];
    int run = incl - mysum;           // exclusive prefix of this thread
#pragma unroll
    for (int k = 0; k < 4; ++k) {
        if (base + k < N) rowptr[base + k] = run;
        run += v[k];
    }
    if (t == 255) bsum[b] = incl;
}

__global__ void k_scanB(const int* __restrict__ bsum, int* __restrict__ boff) {
    __shared__ int s[128];
    int t = threadIdx.x;
    s[t] = (t < NB) ? bsum[t] : 0;
    __syncthreads();
    if (t == 0) {
        int run = 0;
        for (int i = 0; i < NB; ++i) { int v = s[i]; boff[i] = run; run += v; }
    }
}

__global__ void k_scanC(int* __restrict__ rowptr, const int* __restrict__ boff,
                        int* __restrict__ cursor) {
    int i = blockIdx.x * blockDim.x + threadIdx.x;
    if (i < N) {
        int r = rowptr[i] + boff[i >> 10];
        rowptr[i] = r;
        cursor[i] = r;
    }
}

// ---------------- CSR placement: ecol[pos]=src, ewgt[pos]=dis[src] ----------------
__global__ void k_place(const int* __restrict__ src, const int* __restrict__ dst,
                        const float* __restrict__ dis, int* __restrict__ cursor,
                        int* __restrict__ ecol, float* __restrict__ ewgt) {
    int e = blockIdx.x * blockDim.x + threadIdx.x;
    if (e >= E) return;
    int d = dst[e], s = src[e];
    int pos = atomicAdd(&cursor[d], 1);
    ecol[pos] = s;
    ewgt[pos] = dis[s];
}

// ---------------- dense GEMM  H[N,COUT] = X[N,CIN] @ W[CIN,COUT] ----------------
template <int CIN, int COUT>
__global__ void k_gemm(const float* __restrict__ X, const float* __restrict__ W,
                       float* __restrict__ H) {
    constexpr int ROWS = 256 / COUT;
    __shared__ float sW[CIN * COUT];
    __shared__ float sX[ROWS][CIN];
    for (int i = threadIdx.x; i < CIN * COUT; i += 256) sW[i] = W[i];
    int row0 = blockIdx.x * ROWS;
    for (int i = threadIdx.x; i < ROWS * CIN; i += 256) {
        int r = i / CIN, c = i % CIN;
        int gr = row0 + r;
        sX[r][c] = (gr < N) ? X[(long)gr * CIN + c] : 0.f;
    }
    __syncthreads();
    int r = threadIdx.x / COUT;
    int c = threadIdx.x % COUT;
    int gr = row0 + r;
    if (gr >= N) return;
    float acc = 0.f;
#pragma unroll
    for (int k = 0; k < CIN; ++k) acc += sX[r][k] * sW[k * COUT + c];
    H[(long)gr * COUT + c] = acc;
}

// ---------------- gather layer 1: agg1 = relu(D^-1/2 A D^-1/2 h1 + b1) ----------------
// one 64-lane wave per node; lane = channel
__global__ void k_gather1(const float* __restrict__ h1, const float* __restrict__ dis,
                          const int* __restrict__ rowptr, const int* __restrict__ deg,
                          const int* __restrict__ ecol, const float* __restrict__ ewgt,
                          const float* __restrict__ b1, float* __restrict__ agg1) {
    int node = (blockIdx.x * 256 + threadIdx.x) >> 6;
    int lane = threadIdx.x & 63;
    if (node >= N) return;
    float di = dis[node];
    float acc = di * h1[(long)node * C2 + lane];     // self-loop term (×di again below)
    int start = rowptr[node];
    int dgr = deg[node];
    for (int j = 0; j < dgr; ++j) {
        int s = ecol[start + j];
        float w = ewgt[start + j];
        acc += w * h1[(long)s * C2 + lane];
    }
    float v = di * acc + b1[lane];
    agg1[(long)node * C2 + lane] = fmaxf(v, 0.f);
}

// ---------------- gather layer 2 + log_softmax: 32 lanes per node ----------------
__global__ void k_gather2(const float* __restrict__ h2, const float* __restrict__ dis,
                          const int* __restrict__ rowptr, const int* __restrict__ deg,
                          const int* __restrict__ ecol, const float* __restrict__ ewgt,
                          const float* __restrict__ b2, float* __restrict__ out) {
    int gid = blockIdx.x * 256 + threadIdx.x;
    int node = gid >> 5;
    int lane = gid & 31;
    if (node >= N) return;
    float di = dis[node];
    float acc = di * h2[(long)node * C3 + lane];
    int start = rowptr[node];
    int dgr = deg[node];
    for (int j = 0; j < dgr; ++j) {
        int s = ecol[start + j];
        float w = ewgt[start + j];
        acc += w * h2[(long)s * C3 + lane];
    }
    float v = di * acc + b2[lane];
    // log_softmax over 32 channels
    float m = v;
#pragma unroll
    for (int off = 16; off >= 1; off >>= 1) m = fmaxf(m, __shfl_xor(m, off, 32));
    float ex = expf(v - m);
    float s2 = ex;
#pragma unroll
    for (int off = 16; off >= 1; off >>= 1) s2 += __shfl_xor(s2, off, 32);
    out[(long)node * C3 + lane] = v - m - logf(s2);
}

extern "C" void kernel_launch(void* const* d_in, const int* in_sizes, int n_in,
                              void* d_out, int out_size, void* d_ws, size_t ws_size,
                              hipStream_t stream) {
    const float* x  = (const float*)d_in[0];
    const int*   ei = (const int*)d_in[1];
    const float* W1 = (const float*)d_in[2];
    const float* b1 = (const float*)d_in[3];
    const float* W2 = (const float*)d_in[4];
    const float* b2 = (const float*)d_in[5];
    float* out = (float*)d_out;

    const int* src = ei;        // edge_index[0]
    const int* dst = ei + E;    // edge_index[1]

    char* w = (char*)d_ws;
    int*   deg    = (int*)(w + 0);                 // 0.4 MB
    float* dis    = (float*)(w + (512u << 10));    // 0.4 MB
    int*   rowptr = (int*)(w + (1024u << 10));     // 0.4 MB
    int*   cursor = (int*)(w + (1536u << 10));     // 0.4 MB
    int*   bsum   = (int*)(w + (2048u << 10));     // ~0.4 KB
    int*   boff   = (int*)(w + (2048u << 10) + 4096);
    int*   ecol   = (int*)(w + (2560u << 10));     // 3.2 MB
    float* ewgt   = (float*)(w + (6144u << 10));   // 3.2 MB
    float* h1     = (float*)(w + (10240u << 10));  // 25.6 MB (reused as h2)
    float* agg1   = (float*)(w + (36864u << 10));  // 25.6 MB
    float* h2     = h1;                            // h1 dead after gather1

    hipMemsetAsync(deg, 0, (size_t)N * 4, stream);
    k_degree<<<(E + 255) / 256, 256, 0, stream>>>(dst, deg);
    k_dis<<<(N + 255) / 256, 256, 0, stream>>>(deg, dis);

    // CSR build
    k_scanA<<<NB, 256, 0, stream>>>(deg, rowptr, bsum);
    k_scanB<<<1, 128, 0, stream>>>(bsum, boff);
    k_scanC<<<(N + 255) / 256, 256, 0, stream>>>(rowptr, boff, cursor);
    k_place<<<(E + 255) / 256, 256, 0, stream>>>(src, dst, dis, cursor, ecol, ewgt);

    // layer 1
    k_gemm<C1, C2><<<(N + 3) / 4, 256, 0, stream>>>(x, W1, h1);
    k_gather1<<<(N + 3) / 4, 256, 0, stream>>>(h1, dis, rowptr, deg, ecol, ewgt, b1, agg1);

    // layer 2
    k_gemm<C2, C3><<<(N + 7) / 8, 256, 0, stream>>>(agg1, W2, h2);
    k_gather2<<<(N + 7) / 8, 256, 0, stream>>>(h2, dis, rowptr, deg, ecol, ewgt, b2, out);
}